// Round 11
// baseline (2330.499 us; speedup 1.0000x reference)
//
#include <hip/hip_runtime.h>

#define T_STEPS 1000
#define NIN     128
#define NREC    512
#define NBATCH  64
#define ALPHA   0.2f

#define NSLICE  4          // blocks per batch element
#define SCOLS   128        // columns per slice (512/4)
#define NGRP    8          // k-groups per block (1024 threads / 128)
#define KPER    64         // k elements per group

// d_ws layout (bytes):
//   [0, 1MB)            W_eff (512x512 fp32)
//   [1MB, +512KB)       comm  (LLC slots): 2 parities x 64 x 512 u64 {tag,h}
//   [1.5MB, +512KB)     comm2 (L2 slots):  same layout, plain-store path
#define WS_W_OFF      0
#define WS_COMM_OFF   (1u << 20)
#define COMM_U64      (NBATCH * NREC)              // u64 elements per parity
#define COMM_BYTES    (2 * COMM_U64 * 8)           // 512 KB
#define WS_COMM2_OFF  (WS_COMM_OFF + COMM_BYTES)
#define WS_NEEDED_LLC (WS_COMM_OFF + COMM_BYTES)
#define WS_NEEDED_DUAL (WS_COMM2_OFF + COMM_BYTES)

// LDS-only barrier (proven r6-r10): drains LDS ops, NOT vmcnt.
#define LDS_BARRIER() do {                                        \
    asm volatile("s_waitcnt lgkmcnt(0)" ::: "memory");            \
    __builtin_amdgcn_s_barrier();                                 \
    asm volatile("" ::: "memory");                                \
} while (0)

// --- comm primitives ---------------------------------------------------
__device__ __forceinline__ unsigned long long ld_l2(
        const unsigned long long* p) {
    unsigned long long r;
    asm volatile("global_load_dwordx2 %0, %1, off sc0\n\t"
                 "s_waitcnt vmcnt(0)"
                 : "=v"(r) : "v"(p) : "memory");
    return r;
}
__device__ __forceinline__ void st_l2(unsigned long long* p,
                                      unsigned long long v) {
    asm volatile("global_store_dwordx2 %0, %1, off"
                 :: "v"(p), "v"(v) : "memory");
}
__device__ __forceinline__ unsigned long long ld_llc(
        const unsigned long long* p) {
    return __hip_atomic_load(p, __ATOMIC_RELAXED, __HIP_MEMORY_SCOPE_AGENT);
}
__device__ __forceinline__ void st_llc(unsigned long long* p,
                                       unsigned long long v) {
    __hip_atomic_store(p, v, __ATOMIC_RELAXED, __HIP_MEMORY_SCOPE_AGENT);
}

// ---------------------------------------------------------------------------
// W_eff[k][j] = ei[k] * w_rec[k][j] * autapse[k][j]
// ---------------------------------------------------------------------------
__global__ void weff_kernel(const float* __restrict__ w_rec,
                            const float* __restrict__ ei_mask,
                            const float* __restrict__ autapse,
                            float* __restrict__ w_eff) {
    int idx = blockIdx.x * blockDim.x + threadIdx.x;
    if (idx < NREC * NREC) {
        int row = idx >> 9;
        float ei = ei_mask[row * NREC + row];
        w_eff[idx] = ei * w_rec[idx] * autapse[idx];
    }
}

// ---------------------------------------------------------------------------
// inp_all[m][j] = sum_k x[m][k] * w_in[k][j] + b_rec[j]   (into d_out)
// ---------------------------------------------------------------------------
__global__ __launch_bounds__(1024) void gemm_in_kernel(
        const float* __restrict__ x,
        const float* __restrict__ w_in,
        const float* __restrict__ b_rec,
        float* __restrict__ io) {
    __shared__ float xs[32][NIN];

    const int tid = threadIdx.x;
    const int m0  = blockIdx.x * 32;

    {
        const float4* src = reinterpret_cast<const float4*>(x + (size_t)m0 * NIN);
        reinterpret_cast<float4*>(&xs[0][0])[tid] = src[tid];
    }
    __syncthreads();

    const int j0 = tid & 255;
    const int j1 = j0 + 256;
    const int rg = tid >> 8;

    float acc[8][2];
#pragma unroll
    for (int i = 0; i < 8; ++i) { acc[i][0] = 0.f; acc[i][1] = 0.f; }

#pragma unroll 4
    for (int k = 0; k < NIN; ++k) {
        float wv0 = w_in[k * NREC + j0];
        float wv1 = w_in[k * NREC + j1];
#pragma unroll
        for (int i = 0; i < 8; ++i) {
            float xv = xs[rg * 8 + i][k];
            acc[i][0] = fmaf(xv, wv0, acc[i][0]);
            acc[i][1] = fmaf(xv, wv1, acc[i][1]);
        }
    }

    const float br0 = b_rec[j0];
    const float br1 = b_rec[j1];
#pragma unroll
    for (int i = 0; i < 8; ++i) {
        size_t ro = (size_t)(m0 + rg * 8 + i) * NREC;
        io[ro + j0] = acc[i][0] + br0;
        io[ro + j1] = acc[i][1] + br1;
    }
}

// ---------------------------------------------------------------------------
// Cooperative recurrence -- r10 base + two fixes:
// (1) io/noise prefetch moved OFF polling waves: the 4 own-slice waves
//     ("loaders", g>>1==s, never poll) load row t+1 at the top of step t
//     and write it to parity-buffered ldsin after B1; leaders consume from
//     LDS at step t+1. Polling waves carry no in-flight HBM loads, so the
//     poll's vmcnt(0) no longer absorbs ~900cy of prefetch latency.
// (2) L2-dominant poll: 3x sc0 (XCD-local L2, ~200cy) per 1x LLC safety
//     check (cross-XCD termination guaranteed).
// ---------------------------------------------------------------------------
__global__ __launch_bounds__(1024, 4) void rnn_coop(
        const float* __restrict__ W,
        const float* __restrict__ noise,
        float* __restrict__ io,
        unsigned long long* __restrict__ comm,     // LLC slots
        unsigned long long* __restrict__ comm2) {  // L2 slots (may be null)
    __shared__ __align__(16) float h_lds[NREC];
    __shared__ float part[NGRP * SCOLS];
    __shared__ float ldsin[2][2][SCOLS];           // [parity][io|noise][col]

    const int tid = threadIdx.x;
    const int bid = blockIdx.x;
    const int b   = (bid & 7) + 8 * (bid >> 5);    // batch: slices share bid%8
    const int s   = (bid >> 3) & 3;
    const int jl  = tid & (SCOLS - 1);
    const int g   = tid >> 7;              // 0..7
    const int ln  = tid & 63;
    const int jg  = s * SCOLS + jl;
    const bool remote = (g >> 1) != s;     // this k-group's h slice is remote
    const int cslot = g * KPER + ln;       // h index this lane gathers
    const bool use_l2 = (comm2 != nullptr);

    // loader role: the own-slice threads (never poll), 256 of them
    const int  lt        = tid - s * 256;
    const bool is_loader = (lt >= 0) && (lt < 256);
    const int  lwhich    = (lt >> 7) & 1;          // 0: io, 1: noise
    const int  lcol      = lt & (SCOLS - 1);
    const float* lsrc    = lwhich ? noise : io;
    const size_t lbase   = (size_t)b * T_STEPS * NREC + s * SCOLS + lcol;

    // one-time W slice load (coalesced), then pin (AGPR-resident is fine on
    // gfx950's unified file -- direct VALU operand reads)
    float Wr[KPER];
    {
        const float* wp = W + (size_t)(g * KPER) * NREC + jg;
#pragma unroll
        for (int u = 0; u < KPER; ++u)
            Wr[u] = wp[(size_t)u * NREC];
    }
#pragma unroll
    for (int u = 0; u < KPER; ++u)
        asm volatile("" : "+v"(Wr[u]));

    if (tid < NREC) h_lds[tid] = 0.f;
    if (is_loader) ldsin[0][lwhich][lcol] = lsrc[lbase];   // row 0 preload
    __syncthreads();

    float hj = 0.f;                        // leaders' (tid<128) own h
    const size_t iobase = (size_t)b * T_STEPS * NREC + jg;
    const unsigned long long* cbase  = comm  + (size_t)b * NREC + cslot;
    const unsigned long long* cbase2 = comm2 + (size_t)b * NREC + cslot;
    unsigned long long* cwr  = comm  + (size_t)b * NREC + jg;
    unsigned long long* cwr2 = comm2 + (size_t)b * NREC + jg;

    for (int t = 0; t < T_STEPS; ++t) {
        const int p = t & 1;

        // loaders: issue NEXT row's loads now; latency hides under compute
        // and the peers' poll phase; value written to LDS after B1.
        float lv = 0.f;
        const bool lactive = is_loader && (t + 1 < T_STEPS);
        if (lactive)
            lv = lsrc[lbase + (size_t)(t + 1) * NREC];

        if (t > 0 && remote) {
            const size_t po = (size_t)p * COMM_U64;
            unsigned long long v;
            if (use_l2) {
                v = ld_l2(cbase2 + po);                 // fast local path
                int it = 0;
                while ((int)(unsigned)(v >> 32) < t) {
                    if ((++it & 3) == 0) {
                        v = ld_llc(cbase + po);         // safety net (1 in 4)
                    } else {
                        v = ld_l2(cbase2 + po);
                    }
                }
            } else {
                v = ld_llc(cbase + po);
                while ((int)(unsigned)(v >> 32) < t)
                    v = ld_llc(cbase + po);
            }
            asm volatile("" ::: "memory");
            // both waves of group g write the same 64 slots w/ same value
            h_lds[cslot] = __uint_as_float((unsigned)(v & 0xffffffffu));
        }

        // 64-long partial dot (plain fmaf: compiler batches the ds_reads)
        float a0 = 0.f, a1 = 0.f, a2 = 0.f, a3 = 0.f;
        const float4* h4 = reinterpret_cast<const float4*>(&h_lds[g * KPER]);
#pragma unroll
        for (int u = 0; u < KPER / 4; ++u) {
            float4 hv = h4[u];
            a0 = fmaf(hv.x, Wr[4 * u + 0], a0);
            a1 = fmaf(hv.y, Wr[4 * u + 1], a1);
            a2 = fmaf(hv.z, Wr[4 * u + 2], a2);
            a3 = fmaf(hv.w, Wr[4 * u + 3], a3);
        }
        part[g * SCOLS + jl] = (a0 + a1) + (a2 + a3);
        LDS_BARRIER();                                 // B1: partials ready

        if (tid < SCOLS) {                             // leader waves 0,1
            float inp = ldsin[p][0][jl];
            float nz  = ldsin[p][1][jl];
            float pre = inp + nz;
#pragma unroll
            for (int q = 0; q < NGRP; ++q)
                pre += part[q * SCOLS + jl];
            float hnew = (1.f - ALPHA) * hj + ALPHA * fmaxf(pre, 0.f);
            hj = hnew;
            h_lds[jg] = hnew;                          // own slice for t+1
            unsigned long long pv =
                ((unsigned long long)(unsigned)(t + 1) << 32) |
                (unsigned long long)__float_as_uint(hnew);
            const size_t po = (size_t)((t + 1) & 1) * COMM_U64;
            if (use_l2) st_l2(cwr2 + po, pv);          // fast local publish
            st_llc(cwr + po, pv);                      // guaranteed publish
            io[iobase + (size_t)t * NREC] = hnew;      // trajectory output
        }

        // loaders: deposit row t+1 for the next leader phase (idle window;
        // compiler inserts the vmcnt wait for lv here, ~1000cy after issue)
        if (lactive)
            ldsin[p ^ 1][lwhich][lcol] = lv;

        LDS_BARRIER();                                 // B2: h_lds/ldsin ready
    }
}

// ---------------------------------------------------------------------------
// Fallback (round-1 kernel) if ws_size is too small for comm buffers.
// ---------------------------------------------------------------------------
__global__ __launch_bounds__(1024) void rnn_kernel(
        const float* __restrict__ W,
        const float* __restrict__ noise,
        float* __restrict__ io) {
    __shared__ float h[NREC];
    __shared__ float part2[NREC];

    const int tid  = threadIdx.x;
    const int j    = tid & (NREC - 1);
    const int half = tid >> 9;
    const int b    = blockIdx.x;

    if (tid < NREC) h[tid] = 0.f;
    float hj = 0.f;
    __syncthreads();

    const int kb = half * 256;
    const float* wp = W + (size_t)kb * NREC + j;
    const size_t base = (size_t)b * T_STEPS * NREC + j;

    for (int t = 0; t < T_STEPS; ++t) {
        const size_t off = base + (size_t)t * NREC;
        float acc = (half == 0) ? (io[off] + noise[off]) : 0.f;
#pragma unroll
        for (int ku = 0; ku < 256; ku += 16) {
            float w[16];
#pragma unroll
            for (int u = 0; u < 16; ++u) w[u] = wp[(size_t)(ku + u) * NREC];
#pragma unroll
            for (int u = 0; u < 16; ++u) acc = fmaf(h[kb + ku + u], w[u], acc);
        }
        if (half == 1) part2[j] = acc;
        __syncthreads();
        if (half == 0) {
            float pre  = acc + part2[j];
            float hnew = (1.f - ALPHA) * hj + ALPHA * fmaxf(pre, 0.f);
            io[off] = hnew;
            h[j] = hnew;
            hj = hnew;
        }
        __syncthreads();
    }
}

// ---------------------------------------------------------------------------
extern "C" void kernel_launch(void* const* d_in, const int* in_sizes, int n_in,
                              void* d_out, int out_size, void* d_ws, size_t ws_size,
                              hipStream_t stream) {
    const float* x       = (const float*)d_in[0];
    const float* w_in    = (const float*)d_in[1];
    const float* w_rec   = (const float*)d_in[2];
    const float* b_rec   = (const float*)d_in[3];
    const float* ei_mask = (const float*)d_in[4];
    const float* autapse = (const float*)d_in[5];
    const float* noise   = (const float*)d_in[6];
    float* out = (float*)d_out;

    char* ws = (char*)d_ws;
    float* W = (float*)(ws + WS_W_OFF);
    unsigned long long* comm  = (unsigned long long*)(ws + WS_COMM_OFF);
    unsigned long long* comm2 = (unsigned long long*)(ws + WS_COMM2_OFF);

    weff_kernel<<<dim3((NREC * NREC + 255) / 256), dim3(256), 0, stream>>>(
        w_rec, ei_mask, autapse, W);

    gemm_in_kernel<<<dim3(64000 / 32), dim3(1024), 0, stream>>>(
        x, w_in, b_rec, out);

    if (ws_size >= (size_t)WS_NEEDED_DUAL) {
        hipMemsetAsync(comm, 0, 2 * COMM_BYTES, stream);   // both slot arrays
        void* args[] = {(void*)&W, (void*)&noise, (void*)&out,
                        (void*)&comm, (void*)&comm2};
        hipLaunchCooperativeKernel(reinterpret_cast<void*>(rnn_coop),
                                   dim3(NBATCH * NSLICE), dim3(1024),
                                   args, 0, stream);
    } else if (ws_size >= (size_t)WS_NEEDED_LLC) {
        hipMemsetAsync(comm, 0, COMM_BYTES, stream);
        unsigned long long* nul = nullptr;
        void* args[] = {(void*)&W, (void*)&noise, (void*)&out,
                        (void*)&comm, (void*)&nul};
        hipLaunchCooperativeKernel(reinterpret_cast<void*>(rnn_coop),
                                   dim3(NBATCH * NSLICE), dim3(1024),
                                   args, 0, stream);
    } else {
        rnn_kernel<<<dim3(NBATCH), dim3(1024), 0, stream>>>(W, noise, out);
    }
}

// Round 12
// 1676.090 us; speedup vs baseline: 1.3904x; 1.3904x over previous
//
#include <hip/hip_runtime.h>

#define T_STEPS 1000
#define NIN     128
#define NREC    512
#define NBATCH  64
#define ALPHA   0.2f

#define NSLICE  4          // blocks per batch element
#define SCOLS   128        // columns per slice (512/4)
#define NGRP    8          // k-groups per block (16 waves = 8 kgrp x 2 halves)
#define KPER    64         // k elements per group

// d_ws layout (bytes):
//   [0, 1MB)            W_eff (512x512 fp32)
//   [1MB, +512KB)       comm  (LLC slots): 2 parities x 64 x 512 u64 {tag,h}
//   [1.5MB, +512KB)     comm2 (L2 slots):  same layout, plain-store path
#define WS_W_OFF      0
#define WS_COMM_OFF   (1u << 20)
#define COMM_U64      (NBATCH * NREC)              // u64 elements per parity
#define COMM_BYTES    (2 * COMM_U64 * 8)           // 512 KB
#define WS_COMM2_OFF  (WS_COMM_OFF + COMM_BYTES)
#define WS_NEEDED_LLC (WS_COMM_OFF + COMM_BYTES)
#define WS_NEEDED_DUAL (WS_COMM2_OFF + COMM_BYTES)

// LDS-only barrier (proven r6-r11): drains LDS ops, NOT vmcnt.
#define LDS_BARRIER() do {                                        \
    asm volatile("s_waitcnt lgkmcnt(0)" ::: "memory");            \
    __builtin_amdgcn_s_barrier();                                 \
    asm volatile("" ::: "memory");                                \
} while (0)

// --- comm primitives (proven r10) ---------------------------------------
__device__ __forceinline__ unsigned long long ld_l2(
        const unsigned long long* p) {
    unsigned long long r;
    asm volatile("global_load_dwordx2 %0, %1, off sc0\n\t"
                 "s_waitcnt vmcnt(0)"
                 : "=v"(r) : "v"(p) : "memory");
    return r;
}
__device__ __forceinline__ void st_l2(unsigned long long* p,
                                      unsigned long long v) {
    asm volatile("global_store_dwordx2 %0, %1, off"
                 :: "v"(p), "v"(v) : "memory");
}
__device__ __forceinline__ unsigned long long ld_llc(
        const unsigned long long* p) {
    return __hip_atomic_load(p, __ATOMIC_RELAXED, __HIP_MEMORY_SCOPE_AGENT);
}
__device__ __forceinline__ void st_llc(unsigned long long* p,
                                       unsigned long long v) {
    __hip_atomic_store(p, v, __ATOMIC_RELAXED, __HIP_MEMORY_SCOPE_AGENT);
}

// ---------------------------------------------------------------------------
// W_eff[k][j] = ei[k] * w_rec[k][j] * autapse[k][j]
// ---------------------------------------------------------------------------
__global__ void weff_kernel(const float* __restrict__ w_rec,
                            const float* __restrict__ ei_mask,
                            const float* __restrict__ autapse,
                            float* __restrict__ w_eff) {
    int idx = blockIdx.x * blockDim.x + threadIdx.x;
    if (idx < NREC * NREC) {
        int row = idx >> 9;
        float ei = ei_mask[row * NREC + row];
        w_eff[idx] = ei * w_rec[idx] * autapse[idx];
    }
}

// ---------------------------------------------------------------------------
// inp_all[m][j] = sum_k x[m][k] * w_in[k][j] + b_rec[j]   (into d_out)
// ---------------------------------------------------------------------------
__global__ __launch_bounds__(1024) void gemm_in_kernel(
        const float* __restrict__ x,
        const float* __restrict__ w_in,
        const float* __restrict__ b_rec,
        float* __restrict__ io) {
    __shared__ float xs[32][NIN];

    const int tid = threadIdx.x;
    const int m0  = blockIdx.x * 32;

    {
        const float4* src = reinterpret_cast<const float4*>(x + (size_t)m0 * NIN);
        reinterpret_cast<float4*>(&xs[0][0])[tid] = src[tid];
    }
    __syncthreads();

    const int j0 = tid & 255;
    const int j1 = j0 + 256;
    const int rg = tid >> 8;

    float acc[8][2];
#pragma unroll
    for (int i = 0; i < 8; ++i) { acc[i][0] = 0.f; acc[i][1] = 0.f; }

#pragma unroll 4
    for (int k = 0; k < NIN; ++k) {
        float wv0 = w_in[k * NREC + j0];
        float wv1 = w_in[k * NREC + j1];
#pragma unroll
        for (int i = 0; i < 8; ++i) {
            float xv = xs[rg * 8 + i][k];
            acc[i][0] = fmaf(xv, wv0, acc[i][0]);
            acc[i][1] = fmaf(xv, wv1, acc[i][1]);
        }
    }

    const float br0 = b_rec[j0];
    const float br1 = b_rec[j1];
#pragma unroll
    for (int i = 0; i < 8; ++i) {
        size_t ro = (size_t)(m0 + rg * 8 + i) * NREC;
        io[ro + j0] = acc[i][0] + br0;
        io[ro + j1] = acc[i][1] + br1;
    }
}

// ---------------------------------------------------------------------------
// Cooperative recurrence, register-broadcast redesign (kills the LDS floor).
// 256 blocks: batch b (slices share bid%8 -> likely one XCD), slice s.
// 16 waves: wave w -> k-group g=w>>1 (k in [64g,+64)), col-half c=w&1.
// Lane ln: column col=c*64+ln, holds Wr[u]=W[64g+u][s*128+col] (64 regs).
// h delivery (NO bulk LDS reads): lane ln needs exactly h[64g+ln] --
//   remote kgroup: straight from its poll load result (register!)
//   own kgroup (w>>2==s): one ds_read_b32 from h_own (leader-written)
// Dot product: h broadcast via v_readlane -> SGPR -> v_fmac s-operand
// (VALU pipe, 4x wider than the shared LDS pipe).
// Leaders = waves 4s,4s+1 (own-slice, NEVER poll): reduce 8 partials,
// update h, publish {tag,h} dual-path, store io row, prefetch row t+1.
// ---------------------------------------------------------------------------
__global__ __launch_bounds__(1024, 4) void rnn_coop(
        const float* __restrict__ W,
        const float* __restrict__ noise,
        float* __restrict__ io,
        unsigned long long* __restrict__ comm,     // LLC slots
        unsigned long long* __restrict__ comm2) {  // L2 slots (may be null)
    __shared__ float h_own[SCOLS];                 // own-slice h_t
    __shared__ float part[NGRP][SCOLS];            // per-kgroup partials

    const int tid = threadIdx.x;
    const int bid = blockIdx.x;
    const int b   = (bid & 7) + 8 * (bid >> 5);    // slices of b share bid%8
    const int s   = (bid >> 3) & 3;
    const int w   = tid >> 6;              // wave 0..15
    const int ln  = tid & 63;
    const int g   = w >> 1;                // k-group, k in [64g, +64)
    const int c   = w & 1;                 // column half
    const int col = c * 64 + ln;           // 0..127
    const int jg  = s * SCOLS + col;       // global column
    const bool own       = (w >> 2) == s;  // kgroups 2s,2s+1: h is local
    const bool is_leader = own && ((w & 2) == 0);   // waves 4s,4s+1
    const bool use_l2    = (comm2 != nullptr);

    // one-time W slice load (coalesced across lanes), pinned
    float Wr[KPER];
    {
        const float* wp = W + (size_t)(g * KPER) * NREC + jg;
#pragma unroll
        for (int u = 0; u < KPER; ++u)
            Wr[u] = wp[(size_t)u * NREC];
    }
#pragma unroll
    for (int u = 0; u < KPER; ++u)
        asm volatile("" : "+v"(Wr[u]));

    float hj = 0.f;                        // leader's own h_t[col]
    const size_t iobase = (size_t)b * T_STEPS * NREC + jg;
    // poll slot: h index 64g+ln (the one value this lane needs)
    const unsigned long long* cpoll  = comm  + (size_t)b * NREC + g * KPER + ln;
    const unsigned long long* cpoll2 = comm2 + (size_t)b * NREC + g * KPER + ln;
    // publish slot: this leader's column
    unsigned long long* cwr  = comm  + (size_t)b * NREC + jg;
    unsigned long long* cwr2 = comm2 + (size_t)b * NREC + jg;

    // leaders prefetch row 0
    float inp = 0.f, nz = 0.f;
    if (is_leader) { inp = io[iobase]; nz = noise[iobase]; }

    for (int t = 0; t < T_STEPS; ++t) {
        // ---- acquire h_t[64g+ln] into a register ----
        float hval;
        if (t == 0) {
            hval = 0.f;
        } else if (own) {
            hval = h_own[(g & 1) * KPER + ln];      // 1 ds_read_b32/wave
        } else {
            const size_t po = (size_t)(t & 1) * COMM_U64;
            unsigned long long v;
            if (use_l2) {
                v = ld_l2(cpoll2 + po);             // XCD-local fast path
                while ((int)(unsigned)(v >> 32) < t) {
                    v = ld_llc(cpoll + po);         // safety net
                    if ((int)(unsigned)(v >> 32) >= t) break;
                    v = ld_l2(cpoll2 + po);
                }
            } else {
                v = ld_llc(cpoll + po);
                while ((int)(unsigned)(v >> 32) < t)
                    v = ld_llc(cpoll + po);
            }
            hval = __uint_as_float((unsigned)(v & 0xffffffffu));
        }

        // ---- 64-long dot: readlane broadcast (VALU), W in regs ----
        float a0 = 0.f, a1 = 0.f;
#pragma unroll
        for (int u = 0; u < KPER; u += 2) {
            float h0 = __uint_as_float(
                __builtin_amdgcn_readlane(__float_as_uint(hval), u));
            float h1 = __uint_as_float(
                __builtin_amdgcn_readlane(__float_as_uint(hval), u + 1));
            a0 = fmaf(h0, Wr[u],     a0);
            a1 = fmaf(h1, Wr[u + 1], a1);
        }
        part[g][col] = a0 + a1;                     // 1 ds_write_b32/wave
        LDS_BARRIER();                              // B1: partials ready

        if (is_leader) {
            float pre = inp + nz;
#pragma unroll
            for (int q = 0; q < NGRP; ++q)
                pre += part[q][col];                // 8 ds_read_b32
            float hnew = (1.f - ALPHA) * hj + ALPHA * fmaxf(pre, 0.f);
            hj = hnew;
            h_own[col] = hnew;                      // own slice for t+1
            unsigned long long pv =
                ((unsigned long long)(unsigned)(t + 1) << 32) |
                (unsigned long long)__float_as_uint(hnew);
            const size_t po = (size_t)((t + 1) & 1) * COMM_U64;
            if (use_l2) st_l2(cwr2 + po, pv);       // fast local publish
            st_llc(cwr + po, pv);                   // guaranteed publish
            io[iobase + (size_t)t * NREC] = hnew;   // trajectory row t
            if (t + 1 < T_STEPS) {                  // prefetch row t+1
                inp = io[iobase + (size_t)(t + 1) * NREC];
                nz  = noise[iobase + (size_t)(t + 1) * NREC];
            }
        }
        LDS_BARRIER();                              // B2: h_own ready
    }
}

// ---------------------------------------------------------------------------
// Fallback (round-1 kernel) if ws_size is too small for comm buffers.
// ---------------------------------------------------------------------------
__global__ __launch_bounds__(1024) void rnn_kernel(
        const float* __restrict__ W,
        const float* __restrict__ noise,
        float* __restrict__ io) {
    __shared__ float h[NREC];
    __shared__ float part2[NREC];

    const int tid  = threadIdx.x;
    const int j    = tid & (NREC - 1);
    const int half = tid >> 9;
    const int b    = blockIdx.x;

    if (tid < NREC) h[tid] = 0.f;
    float hj = 0.f;
    __syncthreads();

    const int kb = half * 256;
    const float* wp = W + (size_t)kb * NREC + j;
    const size_t base = (size_t)b * T_STEPS * NREC + j;

    for (int t = 0; t < T_STEPS; ++t) {
        const size_t off = base + (size_t)t * NREC;
        float acc = (half == 0) ? (io[off] + noise[off]) : 0.f;
#pragma unroll
        for (int ku = 0; ku < 256; ku += 16) {
            float wv[16];
#pragma unroll
            for (int u = 0; u < 16; ++u) wv[u] = wp[(size_t)(ku + u) * NREC];
#pragma unroll
            for (int u = 0; u < 16; ++u) acc = fmaf(h[kb + ku + u], wv[u], acc);
        }
        if (half == 1) part2[j] = acc;
        __syncthreads();
        if (half == 0) {
            float pre  = acc + part2[j];
            float hnew = (1.f - ALPHA) * hj + ALPHA * fmaxf(pre, 0.f);
            io[off] = hnew;
            h[j] = hnew;
            hj = hnew;
        }
        __syncthreads();
    }
}

// ---------------------------------------------------------------------------
extern "C" void kernel_launch(void* const* d_in, const int* in_sizes, int n_in,
                              void* d_out, int out_size, void* d_ws, size_t ws_size,
                              hipStream_t stream) {
    const float* x       = (const float*)d_in[0];
    const float* w_in    = (const float*)d_in[1];
    const float* w_rec   = (const float*)d_in[2];
    const float* b_rec   = (const float*)d_in[3];
    const float* ei_mask = (const float*)d_in[4];
    const float* autapse = (const float*)d_in[5];
    const float* noise   = (const float*)d_in[6];
    float* out = (float*)d_out;

    char* ws = (char*)d_ws;
    float* W = (float*)(ws + WS_W_OFF);
    unsigned long long* comm  = (unsigned long long*)(ws + WS_COMM_OFF);
    unsigned long long* comm2 = (unsigned long long*)(ws + WS_COMM2_OFF);

    weff_kernel<<<dim3((NREC * NREC + 255) / 256), dim3(256), 0, stream>>>(
        w_rec, ei_mask, autapse, W);

    gemm_in_kernel<<<dim3(64000 / 32), dim3(1024), 0, stream>>>(
        x, w_in, b_rec, out);

    if (ws_size >= (size_t)WS_NEEDED_DUAL) {
        hipMemsetAsync(comm, 0, 2 * COMM_BYTES, stream);   // both slot arrays
        void* args[] = {(void*)&W, (void*)&noise, (void*)&out,
                        (void*)&comm, (void*)&comm2};
        hipLaunchCooperativeKernel(reinterpret_cast<void*>(rnn_coop),
                                   dim3(NBATCH * NSLICE), dim3(1024),
                                   args, 0, stream);
    } else if (ws_size >= (size_t)WS_NEEDED_LLC) {
        hipMemsetAsync(comm, 0, COMM_BYTES, stream);
        unsigned long long* nul = nullptr;
        void* args[] = {(void*)&W, (void*)&noise, (void*)&out,
                        (void*)&comm, (void*)&nul};
        hipLaunchCooperativeKernel(reinterpret_cast<void*>(rnn_coop),
                                   dim3(NBATCH * NSLICE), dim3(1024),
                                   args, 0, stream);
    } else {
        rnn_kernel<<<dim3(NBATCH), dim3(1024), 0, stream>>>(W, noise, out);
    }
}